// Round 2
// baseline (345.261 us; speedup 1.0000x reference)
//
#include <hip/hip_runtime.h>

// MHA: B=8, H=8, S=1024, E=512, KEY_DIM=512, dh=64. fp32 I/O, bf16 MFMA, fp32 accum.

typedef __bf16 bf16x8 __attribute__((ext_vector_type(8)));
typedef float  f32x4  __attribute__((ext_vector_type(4)));

#define MFMA(a, b, c) __builtin_amdgcn_mfma_f32_16x16x32_bf16((a), (b), (c), 0, 0, 0)

__device__ inline bf16x8 cvt8(const float* p) {
  f32x4 u = *(const f32x4*)p;
  f32x4 v = *(const f32x4*)(p + 4);
  bf16x8 r;
  r[0] = (__bf16)u[0]; r[1] = (__bf16)u[1]; r[2] = (__bf16)u[2]; r[3] = (__bf16)u[3];
  r[4] = (__bf16)v[0]; r[5] = (__bf16)v[1]; r[6] = (__bf16)v[2]; r[7] = (__bf16)v[3];
  return r;
}

// ---------------------------------------------------------------------------
// Transpose fp32 512x512 -> bf16 [n][k]. Grid: 64 blocks x 256 threads.
// ---------------------------------------------------------------------------
__global__ __launch_bounds__(256) void transpose512(const float* __restrict__ in,
                                                    __bf16* __restrict__ out) {
  __shared__ __align__(16) float t[64][65];
  const int tk = (blockIdx.x & 7) * 64;
  const int tn = (blockIdx.x >> 3) * 64;
  const int r0 = threadIdx.x >> 4;  // 0..15
  const int c4 = threadIdx.x & 15;  // 0..15
#pragma unroll
  for (int i = 0; i < 4; ++i) {
    int r = r0 + i * 16;
    f32x4 v = *(const f32x4*)(in + (long)(tk + r) * 512 + tn + c4 * 4);
#pragma unroll
    for (int j = 0; j < 4; ++j) t[r][c4 * 4 + j] = v[j];
  }
  __syncthreads();
  const int n0 = threadIdx.x >> 3;  // 0..31
  const int k8 = threadIdx.x & 7;   // 0..7
#pragma unroll
  for (int i = 0; i < 2; ++i) {
    int n = n0 + i * 32;
    bf16x8 v;
#pragma unroll
    for (int j = 0; j < 8; ++j) v[j] = (__bf16)t[k8 * 8 + j][n];
    *(bf16x8*)(out + (long)(tn + n) * 512 + tk + k8 * 8) = v;
  }
}

// ---------------------------------------------------------------------------
// C = X[M,512] @ W[512,512] + bias (Wt[n][k] bf16, bias fp32).
// Block: 256 thr = 4 waves, 128x128 tile; wave = 64x64 (4x4 MFMA 16x16x32).
// MODE 0: out fp32 [m*512+n]
// MODE 1: out bf16 [((b*8+h)*1024+s)*64+d]   (split heads [B,H,S,dh])
// MODE 2: out bf16 [((b*8+h)*64+d)*1024+s]   (split heads [B,H,dh,S] transposed)
// ---------------------------------------------------------------------------
template <int MODE, typename XT, typename OT>
__global__ __launch_bounds__(256) void gemm_k(const XT* __restrict__ X,
                                              const __bf16* __restrict__ Wt,
                                              const float* __restrict__ bias,
                                              OT* __restrict__ out) {
  const int lane = threadIdx.x & 63;
  const int wid = threadIdx.x >> 6;
  const int quad = lane >> 4;
  const int l16 = lane & 15;
  const int bm = (blockIdx.x >> 2) * 128;
  const int bn = (blockIdx.x & 3) * 128;
  const int wm = bm + (wid >> 1) * 64;
  const int wn = bn + (wid & 1) * 64;

  f32x4 acc[4][4] = {};

  const XT* Xp = X + (long)(wm + l16) * 512 + quad * 8;
  const __bf16* Wp = Wt + (long)(wn + l16) * 512 + quad * 8;

  for (int k0 = 0; k0 < 512; k0 += 32) {
    bf16x8 a[4], b[4];
#pragma unroll
    for (int t = 0; t < 4; ++t) {
      if constexpr (__is_same(XT, float))
        a[t] = cvt8((const float*)Xp + (long)t * 16 * 512 + k0);
      else
        a[t] = *(const bf16x8*)((const __bf16*)Xp + (long)t * 16 * 512 + k0);
      b[t] = *(const bf16x8*)(Wp + (long)t * 16 * 512 + k0);
    }
#pragma unroll
    for (int mt = 0; mt < 4; ++mt)
#pragma unroll
      for (int nt = 0; nt < 4; ++nt) acc[mt][nt] = MFMA(a[mt], b[nt], acc[mt][nt]);
  }

#pragma unroll
  for (int nt = 0; nt < 4; ++nt) {
    const int n = wn + nt * 16 + l16;
    const float bv = bias[n];
    const int h = n >> 6, d = n & 63;
#pragma unroll
    for (int mt = 0; mt < 4; ++mt) {
#pragma unroll
      for (int r = 0; r < 4; ++r) {
        const int m = wm + mt * 16 + quad * 4 + r;
        const float v = acc[mt][nt][r] + bv;
        if (MODE == 0) {
          out[(long)m * 512 + n] = (OT)v;
        } else {
          const int bb = m >> 10, s = m & 1023;
          long idx;
          if (MODE == 1)
            idx = ((long)((bb * 8 + h) * 1024 + s)) * 64 + d;
          else
            idx = ((long)((bb * 8 + h) * 64 + d)) * 1024 + s;
          out[idx] = (OT)v;
        }
      }
    }
  }
}

// ---------------------------------------------------------------------------
// Flash attention. Q,K: [B*H, S, 64] bf16; Vt: [B*H, 64, S] bf16; Oc: [B,S,512] bf16.
// One wave = 16 Q-rows; block = 4 waves. Grid = 64 * 16 = 1024.
// ---------------------------------------------------------------------------
__global__ __launch_bounds__(256) void attn(const __bf16* __restrict__ Q,
                                            const __bf16* __restrict__ K,
                                            const __bf16* __restrict__ Vt,
                                            __bf16* __restrict__ Oc) {
  __shared__ __align__(16) __bf16 plds[4][16][32];
  const int lane = threadIdx.x & 63;
  const int wid = threadIdx.x >> 6;
  const int quad = lane >> 4;
  const int l16 = lane & 15;
  const int pair = blockIdx.x >> 4;  // b*8+h
  const int q0 = (blockIdx.x & 15) * 64 + wid * 16;
  const int b = pair >> 3, h = pair & 7;

  const __bf16* Qb = Q + (long)pair * 1024 * 64;
  const __bf16* Kb = K + (long)pair * 1024 * 64;
  const __bf16* Vb = Vt + (long)pair * 64 * 1024;

  bf16x8 aq0 = *(const bf16x8*)(Qb + (q0 + l16) * 64 + quad * 8);
  bf16x8 aq1 = *(const bf16x8*)(Qb + (q0 + l16) * 64 + 32 + quad * 8);

  float mr[4], lr[4];
  f32x4 oa[4] = {};
#pragma unroll
  for (int r = 0; r < 4; ++r) {
    mr[r] = -1e30f;
    lr[r] = 0.f;
  }
  const float scale = 0.04419417382415922f;  // 1/sqrt(512)

  for (int kb = 0; kb < 1024; kb += 32) {
    f32x4 s0 = {}, s1 = {};
    {
      const __bf16* kp0 = Kb + (kb + l16) * 64 + quad * 8;
      const __bf16* kp1 = kp0 + 16 * 64;
      bf16x8 b00 = *(const bf16x8*)(kp0);
      bf16x8 b01 = *(const bf16x8*)(kp0 + 32);
      bf16x8 b10 = *(const bf16x8*)(kp1);
      bf16x8 b11 = *(const bf16x8*)(kp1 + 32);
      s0 = MFMA(aq0, b00, s0);
      s0 = MFMA(aq1, b01, s0);
      s1 = MFMA(aq0, b10, s1);
      s1 = MFMA(aq1, b11, s1);
    }
    float al[4];
    f32x4 p0, p1;
#pragma unroll
    for (int r = 0; r < 4; ++r) {
      float a0 = s0[r] * scale, a1 = s1[r] * scale;
      float rm = fmaxf(a0, a1);
#pragma unroll
      for (int sh = 8; sh >= 1; sh >>= 1) rm = fmaxf(rm, __shfl_xor(rm, sh, 16));
      const float nm = fmaxf(mr[r], rm);
      al[r] = __expf(mr[r] - nm);
      p0[r] = __expf(a0 - nm);
      p1[r] = __expf(a1 - nm);
      float rs = p0[r] + p1[r];
#pragma unroll
      for (int sh = 8; sh >= 1; sh >>= 1) rs += __shfl_xor(rs, sh, 16);
      lr[r] = lr[r] * al[r] + rs;
      mr[r] = nm;
    }
#pragma unroll
    for (int nt = 0; nt < 4; ++nt)
#pragma unroll
      for (int r = 0; r < 4; ++r) oa[nt][r] *= al[r];

    __syncthreads();
#pragma unroll
    for (int r = 0; r < 4; ++r) {
      plds[wid][quad * 4 + r][l16] = (__bf16)p0[r];
      plds[wid][quad * 4 + r][16 + l16] = (__bf16)p1[r];
    }
    __syncthreads();
    bf16x8 pa = *(const bf16x8*)(&plds[wid][l16][quad * 8]);

#pragma unroll
    for (int nt = 0; nt < 4; ++nt) {
      bf16x8 bv = *(const bf16x8*)(Vb + (nt * 16 + l16) * 1024 + kb + quad * 8);
      oa[nt] = MFMA(pa, bv, oa[nt]);
    }
  }

#pragma unroll
  for (int nt = 0; nt < 4; ++nt) {
#pragma unroll
    for (int r = 0; r < 4; ++r) {
      const int row = q0 + quad * 4 + r;
      const int col = h * 64 + nt * 16 + l16;
      Oc[((long)b * 1024 + row) * 512 + col] = (__bf16)(oa[nt][r] / lr[r]);
    }
  }
}

// ---------------------------------------------------------------------------
extern "C" void kernel_launch(void* const* d_in, const int* in_sizes, int n_in,
                              void* d_out, int out_size, void* d_ws, size_t ws_size,
                              hipStream_t stream) {
  const float* queries = (const float*)d_in[0];
  const float* keys = (const float*)d_in[1];
  const float* values = (const float*)d_in[2];
  const float* Wq = (const float*)d_in[3];
  const float* bq = (const float*)d_in[4];
  const float* Wk = (const float*)d_in[5];
  const float* bk = (const float*)d_in[6];
  const float* Wv = (const float*)d_in[7];
  const float* bv = (const float*)d_in[8];
  const float* Wo = (const float*)d_in[9];
  const float* bo = (const float*)d_in[10];
  float* out = (float*)d_out;

  __bf16* ws = (__bf16*)d_ws;
  const long WSZ = 512 * 512;
  __bf16* Wqt = ws;               // bf16 [512,512] transposed
  __bf16* Wkt = ws + WSZ;
  __bf16* Wvt = ws + 2 * WSZ;
  __bf16* Wot = ws + 3 * WSZ;
  __bf16* Qp = ws + 4 * WSZ;      // bf16 [B,H,S,64]
  __bf16* Kp = Qp + 8192L * 512;  // bf16 [B,H,S,64]
  __bf16* Vtp = Kp + 8192L * 512; // bf16 [B,H,64,S]
  __bf16* Oc = Vtp + 8192L * 512; // bf16 [B,S,512]

  transpose512<<<64, 256, 0, stream>>>(Wq, Wqt);
  transpose512<<<64, 256, 0, stream>>>(Wk, Wkt);
  transpose512<<<64, 256, 0, stream>>>(Wv, Wvt);
  transpose512<<<64, 256, 0, stream>>>(Wo, Wot);

  gemm_k<1, float, __bf16><<<256, 256, 0, stream>>>(queries, Wqt, bq, Qp);
  gemm_k<1, float, __bf16><<<256, 256, 0, stream>>>(keys, Wkt, bk, Kp);
  gemm_k<2, float, __bf16><<<256, 256, 0, stream>>>(values, Wvt, bv, Vtp);

  attn<<<1024, 256, 0, stream>>>(Qp, Kp, Vtp, Oc);

  gemm_k<0, __bf16, float><<<256, 256, 0, stream>>>(Oc, Wot, bo, out);
}